// Round 7
// baseline (2924.063 us; speedup 1.0000x reference)
//
#include <hip/hip_runtime.h>

#define DIM   64
#define HID   256
#define TLEN  21
#define BS    65536
#define BLOCK 512
#define WAVES 8
#define ROWS_PER_WAVE 32
#define ROWS_PER_BLOCK 256
#define NBLOCKS (BS / ROWS_PER_BLOCK)   // 256

typedef __bf16    bf16x8   __attribute__((ext_vector_type(8)));
typedef float     f32x16   __attribute__((ext_vector_type(16)));
typedef float     f32x4    __attribute__((ext_vector_type(4)));
typedef float     f32x2    __attribute__((ext_vector_type(2)));
typedef unsigned  uint32x4 __attribute__((ext_vector_type(4)));

__device__ __forceinline__ bf16x8 as_bf16x8(uint32x4 u) {
    return __builtin_bit_cast(bf16x8, u);
}

__device__ __forceinline__ unsigned pack2(float a, float b) {
    __bf16 x = (__bf16)a, y = (__bf16)b;
    unsigned short ux = __builtin_bit_cast(unsigned short, x);
    unsigned short uy = __builtin_bit_cast(unsigned short, y);
    return (unsigned)ux | ((unsigned)uy << 16);
}

// tanh(x) = 1 - 2/(e^{2x}+1). Saturates correctly through exp overflow.
__device__ __forceinline__ float tanh_f(float x) {
    float e = __expf(2.0f * x);
    return 1.0f - __fdividef(2.0f, e + 1.0f);
}

__device__ __forceinline__ uint32x4 pack_lo(f32x16 v) {
    uint32x4 r;
    r[0] = pack2(v[0], v[1]); r[1] = pack2(v[2], v[3]);
    r[2] = pack2(v[4], v[5]); r[3] = pack2(v[6], v[7]);
    return r;
}
__device__ __forceinline__ uint32x4 pack_hi(f32x16 v) {
    uint32x4 r;
    r[0] = pack2(v[8], v[9]);   r[1] = pack2(v[10], v[11]);
    r[2] = pack2(v[12], v[13]); r[3] = pack2(v[14], v[15]);
    return r;
}
// Fused probe: pack2(z + c*k) directly — pa/pb never materialized in fp32.
__device__ __forceinline__ uint32x4 packaxpy_lo(float c, f32x16 k, f32x16 z) {
    uint32x4 r;
    r[0] = pack2(fmaf(c, k[0], z[0]), fmaf(c, k[1], z[1]));
    r[1] = pack2(fmaf(c, k[2], z[2]), fmaf(c, k[3], z[3]));
    r[2] = pack2(fmaf(c, k[4], z[4]), fmaf(c, k[5], z[5]));
    r[3] = pack2(fmaf(c, k[6], z[6]), fmaf(c, k[7], z[7]));
    return r;
}
__device__ __forceinline__ uint32x4 packaxpy_hi(float c, f32x16 k, f32x16 z) {
    uint32x4 r;
    r[0] = pack2(fmaf(c, k[8],  z[8]),  fmaf(c, k[9],  z[9]));
    r[1] = pack2(fmaf(c, k[10], z[10]), fmaf(c, k[11], z[11]));
    r[2] = pack2(fmaf(c, k[12], z[12]), fmaf(c, k[13], z[13]));
    r[3] = pack2(fmaf(c, k[14], z[14]), fmaf(c, k[15], z[15]));
    return r;
}

struct KOut { f32x16 a, b; };

// ---------------------------------------------------------------------------
// Fragment conventions (mfma_f32_32x32x16_bf16, swapped chain) — verified
// (absmax 0.031):
//   matmul1: D1[hid][batch] = A1(W1T) * B1(ztT)   (K = dim, 4 k-tiles)
//   matmul2: D2[dim][batch] = A2(W2T) * B2(tanhT) (K = hid, 16 k-tiles)
// C/D layout: col = lane&31, row_local = (r&3) + 8*(r>>2) + 4*(lane>>5).
// B-frag k->physical map P(g,j) = 4g + (j&3) + 8*(j>>2) so frag word i =
// pack2(x[2i], x[2i+1]) in C/D register order; weights pre-permuted in LDS.
//
// Round-7: VGPR-pressure reduction. R6's counters showed spill-once/
// reload-many traffic (7.4 GB read vs 0.26 GB excess write) => regalloc
// spilling under the 128-VGPR budget. Fixes: (1) probe states pa/pb fused
// into packaxpy (never in fp32 regs), (2) RK4 accumulator zf lives in LDS
// (reuses trbuf; zf dies exactly when the transpose needs the buffer).
// Peak liveness ~110-125 < 128.
// ---------------------------------------------------------------------------

__device__ __forceinline__ KOut feval(const uint32x4* A1, const uint32x4* A2,
                                      const f32x4* b1q, const f32x4* b2q,
                                      int lane, int g,
                                      uint32x4 bk0, uint32x4 bk1,
                                      uint32x4 bk2, uint32x4 bk3)
{
    f32x16 d2a, d2b;
    #pragma unroll
    for (int q = 0; q < 4; q++) {                  // C-in = b2 fragments
        f32x4 ba = b2q[(0 + g) * 4 + q];
        f32x4 bb = b2q[(2 + g) * 4 + q];
        #pragma unroll
        for (int i = 0; i < 4; i++) { d2a[q * 4 + i] = ba[i]; d2b[q * 4 + i] = bb[i]; }
    }

    #pragma unroll
    for (int ht = 0; ht < 8; ht++) {
        f32x16 d1;
        #pragma unroll
        for (int q = 0; q < 4; q++) {              // C-in = b1 fragment
            f32x4 bq = b1q[(ht * 2 + g) * 4 + q];
            #pragma unroll
            for (int i = 0; i < 4; i++) d1[q * 4 + i] = bq[i];
        }
        d1 = __builtin_amdgcn_mfma_f32_32x32x16_bf16(
                 as_bf16x8(A1[(ht * 4 + 0) * 64 + lane]), as_bf16x8(bk0), d1, 0, 0, 0);
        d1 = __builtin_amdgcn_mfma_f32_32x32x16_bf16(
                 as_bf16x8(A1[(ht * 4 + 1) * 64 + lane]), as_bf16x8(bk1), d1, 0, 0, 0);
        d1 = __builtin_amdgcn_mfma_f32_32x32x16_bf16(
                 as_bf16x8(A1[(ht * 4 + 2) * 64 + lane]), as_bf16x8(bk2), d1, 0, 0, 0);
        d1 = __builtin_amdgcn_mfma_f32_32x32x16_bf16(
                 as_bf16x8(A1[(ht * 4 + 3) * 64 + lane]), as_bf16x8(bk3), d1, 0, 0, 0);

        uint32x4 lo, hi;
        lo[0] = pack2(tanh_f(d1[0]),  tanh_f(d1[1]));
        lo[1] = pack2(tanh_f(d1[2]),  tanh_f(d1[3]));
        lo[2] = pack2(tanh_f(d1[4]),  tanh_f(d1[5]));
        lo[3] = pack2(tanh_f(d1[6]),  tanh_f(d1[7]));
        hi[0] = pack2(tanh_f(d1[8]),  tanh_f(d1[9]));
        hi[1] = pack2(tanh_f(d1[10]), tanh_f(d1[11]));
        hi[2] = pack2(tanh_f(d1[12]), tanh_f(d1[13]));
        hi[3] = pack2(tanh_f(d1[14]), tanh_f(d1[15]));

        d2a = __builtin_amdgcn_mfma_f32_32x32x16_bf16(
                  as_bf16x8(A2[(2 * ht) * 64 + lane]), as_bf16x8(lo), d2a, 0, 0, 0);
        d2b = __builtin_amdgcn_mfma_f32_32x32x16_bf16(
                  as_bf16x8(A2[(16 + 2 * ht) * 64 + lane]), as_bf16x8(lo), d2b, 0, 0, 0);
        d2a = __builtin_amdgcn_mfma_f32_32x32x16_bf16(
                  as_bf16x8(A2[(2 * ht + 1) * 64 + lane]), as_bf16x8(hi), d2a, 0, 0, 0);
        d2b = __builtin_amdgcn_mfma_f32_32x32x16_bf16(
                  as_bf16x8(A2[(16 + 2 * ht + 1) * 64 + lane]), as_bf16x8(hi), d2b, 0, 0, 0);
    }

    return KOut{d2a, d2b};
}

extern "C" __global__ __launch_bounds__(BLOCK, 2) void node_mfma_kernel(
    const float* __restrict__ z0, const float* __restrict__ tarr,
    const float* __restrict__ W1, const float* __restrict__ b1,
    const float* __restrict__ W2, const float* __restrict__ b2,
    float* __restrict__ out)
{
    __shared__ __align__(16) unsigned short sA1[32 * 64 * 8];  // 32 KiB
    __shared__ __align__(16) unsigned short sA2[32 * 64 * 8];  // 32 KiB
    __shared__ __align__(16) float sb1[8 * 2 * 16];
    __shared__ __align__(16) float sb2[2 * 2 * 16];
    __shared__ __align__(16) float trbuf[WAVES][2048];  // 8 KiB/wave: zf home + transpose

    const int tid  = threadIdx.x;
    const int lane = tid & 63;
    const int wv   = tid >> 6;
    const int g    = lane >> 5;
    const int ln31 = lane & 31;

    // ---- stage W1 fragments: coalesced global reads, scattered LDS writes ----
    for (int idx = tid; idx < DIM * HID; idx += BLOCK) {
        int hid = idx & (HID - 1);
        int dim = idx >> 8;
        int c   = hid & 31, ht = hid >> 5;
        int j   = (dim & 3) | (((dim >> 3) & 1) << 2);
        int gg  = (dim >> 2) & 1;
        int kt  = dim >> 4;
        __bf16 bv = (__bf16)W1[idx];
        sA1[((ht * 4 + kt) * 64 + gg * 32 + c) * 8 + j] =
            __builtin_bit_cast(unsigned short, bv);
    }
    // ---- stage W2 fragments ----
    for (int idx = tid; idx < HID * DIM; idx += BLOCK) {
        int dim = idx & 63;
        int hid = idx >> 6;
        int c   = dim & 31, mt = dim >> 5;
        int hlo = hid & 15;
        int j   = (hlo & 3) | (((hlo >> 3) & 1) << 2);
        int gg  = (hlo >> 2) & 1;
        int kt2 = hid >> 4;
        __bf16 bv = (__bf16)W2[idx];
        sA2[((mt * 16 + kt2) * 64 + gg * 32 + c) * 8 + j] =
            __builtin_bit_cast(unsigned short, bv);
    }
    // ---- biases, permuted to C/D reg order ----
    if (tid < 256) {
        int r = tid & 15, gg = (tid >> 4) & 1, ht = tid >> 5;
        sb1[tid] = b1[ht * 32 + (r & 3) + 8 * (r >> 2) + 4 * gg];
    }
    if (tid < 64) {
        int r = tid & 15, gg = (tid >> 4) & 1, mt = tid >> 5;
        sb2[tid] = b2[mt * 32 + (r & 3) + 8 * (r >> 2) + 4 * gg];
    }

    // ---- out[0] = z0 (coalesced block-slice copy) ----
    {
        const f32x4* src = reinterpret_cast<const f32x4*>(z0 + (size_t)blockIdx.x * ROWS_PER_BLOCK * DIM);
        f32x4*       dst = reinterpret_cast<f32x4*>(out + (size_t)blockIdx.x * ROWS_PER_BLOCK * DIM);
        for (int i = tid; i < ROWS_PER_BLOCK * DIM / 4; i += BLOCK) dst[i] = src[i];
    }

    __syncthreads();

    const int rowbase = blockIdx.x * ROWS_PER_BLOCK + wv * ROWS_PER_WAVE;
    float* tb = trbuf[wv];
    // zf accumulator home in LDS: pair p of this lane at zfl[p*64] (f32x2).
    // Banks: lane l -> byte l*8 -> 2-way alias = free (m136).
    f32x2* zfl = reinterpret_cast<f32x2*>(tb) + lane;

    const uint32x4* A1  = reinterpret_cast<const uint32x4*>(sA1);
    const uint32x4* A2  = reinterpret_cast<const uint32x4*>(sA2);
    const f32x4*    b1q = reinterpret_cast<const f32x4*>(sb1);
    const f32x4*    b2q = reinterpret_cast<const f32x4*>(sb2);

    // ---- z0 -> registers via per-wave LDS transpose (XOR-swizzled 16B) ----
    #pragma unroll
    for (int p = 0; p < 8; p++) {
        int batch  = (lane >> 4) + 4 * p;
        int linear = lane * 16 + p * 1024;
        f32x4 v = *reinterpret_cast<const f32x4*>(
            z0 + (size_t)(rowbase + batch) * DIM + (lane & 15) * 4);
        *reinterpret_cast<f32x4*>((char*)tb + (linear ^ ((batch & 7) << 4))) = v;
    }

    f32x16 za, zb;
    #pragma unroll
    for (int rp = 0; rp < 8; rp++) {
        int d    = (rp & 1) * 2 + 8 * (rp >> 1) + 4 * g;    // r = 2*rp, mt=0
        int byte = ln31 * 256 + d * 4;
        f32x2 v = *reinterpret_cast<f32x2*>((char*)tb + (byte ^ ((ln31 & 7) << 4)));
        za[2 * rp] = v[0]; za[2 * rp + 1] = v[1];
    }
    #pragma unroll
    for (int rp = 0; rp < 8; rp++) {
        int d    = 32 + (rp & 1) * 2 + 8 * (rp >> 1) + 4 * g;  // mt=1
        int byte = ln31 * 256 + d * 4;
        f32x2 v = *reinterpret_cast<f32x2*>((char*)tb + (byte ^ ((ln31 & 7) << 4)));
        zb[2 * rp] = v[0]; zb[2 * rp + 1] = v[1];
    }

    #pragma unroll 1
    for (int s = 0; s < TLEN - 1; s++) {
        const float h  = tarr[s + 1] - tarr[s];
        const float h2 = 0.5f * h;
        const float h3 = h * (1.0f / 3.0f);
        const float h6 = h * (1.0f / 6.0f);

        // ---- k1 ----
        KOut k1 = feval(A1, A2, b1q, b2q, lane, g,
                        pack_lo(za), pack_hi(za), pack_lo(zb), pack_hi(zb));
        // zf := z + h6*k1  (LDS)
        #pragma unroll
        for (int p = 0; p < 8; p++) {
            f32x2 v; v[0] = fmaf(h6, k1.a[2 * p], za[2 * p]);
                     v[1] = fmaf(h6, k1.a[2 * p + 1], za[2 * p + 1]);
            zfl[p * 64] = v;
        }
        #pragma unroll
        for (int p = 0; p < 8; p++) {
            f32x2 v; v[0] = fmaf(h6, k1.b[2 * p], zb[2 * p]);
                     v[1] = fmaf(h6, k1.b[2 * p + 1], zb[2 * p + 1]);
            zfl[(8 + p) * 64] = v;
        }

        // ---- k2 ----
        KOut k2 = feval(A1, A2, b1q, b2q, lane, g,
                        packaxpy_lo(h2, k1.a, za), packaxpy_hi(h2, k1.a, za),
                        packaxpy_lo(h2, k1.b, zb), packaxpy_hi(h2, k1.b, zb));
        #pragma unroll
        for (int p = 0; p < 8; p++) {
            f32x2 v = zfl[p * 64];
            v[0] = fmaf(h3, k2.a[2 * p], v[0]); v[1] = fmaf(h3, k2.a[2 * p + 1], v[1]);
            zfl[p * 64] = v;
        }
        #pragma unroll
        for (int p = 0; p < 8; p++) {
            f32x2 v = zfl[(8 + p) * 64];
            v[0] = fmaf(h3, k2.b[2 * p], v[0]); v[1] = fmaf(h3, k2.b[2 * p + 1], v[1]);
            zfl[(8 + p) * 64] = v;
        }

        // ---- k3 ----
        KOut k3 = feval(A1, A2, b1q, b2q, lane, g,
                        packaxpy_lo(h2, k2.a, za), packaxpy_hi(h2, k2.a, za),
                        packaxpy_lo(h2, k2.b, zb), packaxpy_hi(h2, k2.b, zb));
        #pragma unroll
        for (int p = 0; p < 8; p++) {
            f32x2 v = zfl[p * 64];
            v[0] = fmaf(h3, k3.a[2 * p], v[0]); v[1] = fmaf(h3, k3.a[2 * p + 1], v[1]);
            zfl[p * 64] = v;
        }
        #pragma unroll
        for (int p = 0; p < 8; p++) {
            f32x2 v = zfl[(8 + p) * 64];
            v[0] = fmaf(h3, k3.b[2 * p], v[0]); v[1] = fmaf(h3, k3.b[2 * p + 1], v[1]);
            zfl[(8 + p) * 64] = v;
        }

        // ---- k4 ----
        KOut k4 = feval(A1, A2, b1q, b2q, lane, g,
                        packaxpy_lo(h, k3.a, za), packaxpy_hi(h, k3.a, za),
                        packaxpy_lo(h, k3.b, zb), packaxpy_hi(h, k3.b, zb));
        // z := zf + h6*k4  (reads zf; zf dead afterwards -> trbuf reusable)
        #pragma unroll
        for (int p = 0; p < 8; p++) {
            f32x2 v = zfl[p * 64];
            za[2 * p]     = fmaf(h6, k4.a[2 * p], v[0]);
            za[2 * p + 1] = fmaf(h6, k4.a[2 * p + 1], v[1]);
        }
        #pragma unroll
        for (int p = 0; p < 8; p++) {
            f32x2 v = zfl[(8 + p) * 64];
            zb[2 * p]     = fmaf(h6, k4.b[2 * p], v[0]);
            zb[2 * p + 1] = fmaf(h6, k4.b[2 * p + 1], v[1]);
        }

        // ---- store trajectory[s+1] via per-wave LDS transpose ----
        #pragma unroll
        for (int rp = 0; rp < 8; rp++) {
            int d    = (rp & 1) * 2 + 8 * (rp >> 1) + 4 * g;
            int byte = ln31 * 256 + d * 4;
            f32x2 v; v[0] = za[2 * rp]; v[1] = za[2 * rp + 1];
            *reinterpret_cast<f32x2*>((char*)tb + (byte ^ ((ln31 & 7) << 4))) = v;
        }
        #pragma unroll
        for (int rp = 0; rp < 8; rp++) {
            int d    = 32 + (rp & 1) * 2 + 8 * (rp >> 1) + 4 * g;
            int byte = ln31 * 256 + d * 4;
            f32x2 v; v[0] = zb[2 * rp]; v[1] = zb[2 * rp + 1];
            *reinterpret_cast<f32x2*>((char*)tb + (byte ^ ((ln31 & 7) << 4))) = v;
        }
        float* obase = out + ((size_t)(s + 1) * BS + rowbase) * DIM;
        #pragma unroll
        for (int p = 0; p < 8; p++) {
            int batch  = (lane >> 4) + 4 * p;
            int linear = lane * 16 + p * 1024;
            f32x4 v = *reinterpret_cast<f32x4*>((char*)tb + (linear ^ ((batch & 7) << 4)));
            *reinterpret_cast<f32x4*>(obase + batch * DIM + (lane & 15) * 4) = v;
        }
    }
}

extern "C" void kernel_launch(void* const* d_in, const int* in_sizes, int n_in,
                              void* d_out, int out_size, void* d_ws, size_t ws_size,
                              hipStream_t stream) {
    const float* z0 = (const float*)d_in[0];
    const float* t  = (const float*)d_in[1];
    const float* W1 = (const float*)d_in[2];
    const float* b1 = (const float*)d_in[3];
    const float* W2 = (const float*)d_in[4];
    const float* b2 = (const float*)d_in[5];
    float* out = (float*)d_out;

    node_mfma_kernel<<<dim3(NBLOCKS), dim3(BLOCK), 0, stream>>>(
        z0, t, W1, b1, W2, b2, out);
}

// Round 8
// 2902.792 us; speedup vs baseline: 1.0073x; 1.0073x over previous
//
#include <hip/hip_runtime.h>

#define DIM   64
#define HID   256
#define TLEN  21
#define BS    65536
#define BLOCK 512
#define WAVES 8
#define ROWS_PER_WAVE 32
#define ROWS_PER_BLOCK 256
#define NBLOCKS (BS / ROWS_PER_BLOCK)   // 256

typedef __bf16    bf16x8   __attribute__((ext_vector_type(8)));
typedef float     f32x16   __attribute__((ext_vector_type(16)));
typedef float     f32x4    __attribute__((ext_vector_type(4)));
typedef float     f32x2    __attribute__((ext_vector_type(2)));
typedef unsigned  uint32x4 __attribute__((ext_vector_type(4)));

__device__ __forceinline__ bf16x8 as_bf16x8(uint32x4 u) {
    return __builtin_bit_cast(bf16x8, u);
}

__device__ __forceinline__ unsigned pack2(float a, float b) {
    __bf16 x = (__bf16)a, y = (__bf16)b;
    unsigned short ux = __builtin_bit_cast(unsigned short, x);
    unsigned short uy = __builtin_bit_cast(unsigned short, y);
    return (unsigned)ux | ((unsigned)uy << 16);
}

// tanh(x) = 1 - 2/(e^{2x}+1). Saturates correctly through exp overflow.
__device__ __forceinline__ float tanh_f(float x) {
    float e = __expf(2.0f * x);
    return 1.0f - __fdividef(2.0f, e + 1.0f);
}

__device__ __forceinline__ uint32x4 pack_lo(f32x16 v) {
    uint32x4 r;
    r[0] = pack2(v[0], v[1]); r[1] = pack2(v[2], v[3]);
    r[2] = pack2(v[4], v[5]); r[3] = pack2(v[6], v[7]);
    return r;
}
__device__ __forceinline__ uint32x4 pack_hi(f32x16 v) {
    uint32x4 r;
    r[0] = pack2(v[8], v[9]);   r[1] = pack2(v[10], v[11]);
    r[2] = pack2(v[12], v[13]); r[3] = pack2(v[14], v[15]);
    return r;
}
__device__ __forceinline__ f32x16 axpy16(float c, f32x16 k, f32x16 z) {
    f32x16 r;
    #pragma unroll
    for (int i = 0; i < 16; i++) r[i] = fmaf(c, k[i], z[i]);
    return r;
}

struct KOut { f32x16 a, b; };

// ---------------------------------------------------------------------------
// Fragment conventions (mfma_f32_32x32x16_bf16, swapped chain) — verified
// (absmax 0.031):
//   matmul1: D1[hid][batch] = A1(W1T) * B1(ztT)   (K = dim, 4 k-tiles)
//   matmul2: D2[dim][batch] = A2(W2T) * B2(tanhT) (K = hid, 16 k-tiles)
// C/D layout: col = lane&31, row_local = (r&3) + 8*(r>>2) + 4*(lane>>5).
// B-frag k->physical map P(g,j) = 4g + (j&3) + 8*(j>>2) so frag word i =
// pack2(x[2i], x[2i+1]) in C/D register order; weights pre-permuted in LDS.
//
// Round-8: amdgpu_waves_per_eu(2,2). VGPR_Count was pinned at exactly 128
// for six rounds regardless of __launch_bounds__ — the backend's occupancy
// heuristic TARGETS 4 waves/EU and spills our ~200-reg state (the invariant
// ~7 GB write-once/read-many FETCH). Pinning the target to 2 waves/EU gives
// regalloc the 256-VGPR budget; HW occupancy is unchanged (LDS already
// limits to 1 block/CU = 2 waves/EU). Structure = round 6 (best, 2.45 ms).
// ---------------------------------------------------------------------------

__device__ __forceinline__ KOut feval(const uint32x4* A1, const uint32x4* A2,
                                      const f32x4* b1q, const f32x4* b2q,
                                      int lane, int g,
                                      uint32x4 bk0, uint32x4 bk1,
                                      uint32x4 bk2, uint32x4 bk3)
{
    f32x16 d2a, d2b;
    #pragma unroll
    for (int q = 0; q < 4; q++) {                  // C-in = b2 fragments
        f32x4 ba = b2q[(0 + g) * 4 + q];
        f32x4 bb = b2q[(2 + g) * 4 + q];
        #pragma unroll
        for (int i = 0; i < 4; i++) { d2a[q * 4 + i] = ba[i]; d2b[q * 4 + i] = bb[i]; }
    }

    #pragma unroll
    for (int ht = 0; ht < 8; ht++) {
        f32x16 d1;
        #pragma unroll
        for (int q = 0; q < 4; q++) {              // C-in = b1 fragment
            f32x4 bq = b1q[(ht * 2 + g) * 4 + q];
            #pragma unroll
            for (int i = 0; i < 4; i++) d1[q * 4 + i] = bq[i];
        }
        d1 = __builtin_amdgcn_mfma_f32_32x32x16_bf16(
                 as_bf16x8(A1[(ht * 4 + 0) * 64 + lane]), as_bf16x8(bk0), d1, 0, 0, 0);
        d1 = __builtin_amdgcn_mfma_f32_32x32x16_bf16(
                 as_bf16x8(A1[(ht * 4 + 1) * 64 + lane]), as_bf16x8(bk1), d1, 0, 0, 0);
        d1 = __builtin_amdgcn_mfma_f32_32x32x16_bf16(
                 as_bf16x8(A1[(ht * 4 + 2) * 64 + lane]), as_bf16x8(bk2), d1, 0, 0, 0);
        d1 = __builtin_amdgcn_mfma_f32_32x32x16_bf16(
                 as_bf16x8(A1[(ht * 4 + 3) * 64 + lane]), as_bf16x8(bk3), d1, 0, 0, 0);

        uint32x4 lo, hi;
        lo[0] = pack2(tanh_f(d1[0]),  tanh_f(d1[1]));
        lo[1] = pack2(tanh_f(d1[2]),  tanh_f(d1[3]));
        lo[2] = pack2(tanh_f(d1[4]),  tanh_f(d1[5]));
        lo[3] = pack2(tanh_f(d1[6]),  tanh_f(d1[7]));
        hi[0] = pack2(tanh_f(d1[8]),  tanh_f(d1[9]));
        hi[1] = pack2(tanh_f(d1[10]), tanh_f(d1[11]));
        hi[2] = pack2(tanh_f(d1[12]), tanh_f(d1[13]));
        hi[3] = pack2(tanh_f(d1[14]), tanh_f(d1[15]));

        d2a = __builtin_amdgcn_mfma_f32_32x32x16_bf16(
                  as_bf16x8(A2[(2 * ht) * 64 + lane]), as_bf16x8(lo), d2a, 0, 0, 0);
        d2b = __builtin_amdgcn_mfma_f32_32x32x16_bf16(
                  as_bf16x8(A2[(16 + 2 * ht) * 64 + lane]), as_bf16x8(lo), d2b, 0, 0, 0);
        d2a = __builtin_amdgcn_mfma_f32_32x32x16_bf16(
                  as_bf16x8(A2[(2 * ht + 1) * 64 + lane]), as_bf16x8(hi), d2a, 0, 0, 0);
        d2b = __builtin_amdgcn_mfma_f32_32x32x16_bf16(
                  as_bf16x8(A2[(16 + 2 * ht + 1) * 64 + lane]), as_bf16x8(hi), d2b, 0, 0, 0);
    }

    return KOut{d2a, d2b};
}

extern "C" __global__ __launch_bounds__(BLOCK)
__attribute__((amdgpu_waves_per_eu(2, 2)))
void node_mfma_kernel(
    const float* __restrict__ z0, const float* __restrict__ tarr,
    const float* __restrict__ W1, const float* __restrict__ b1,
    const float* __restrict__ W2, const float* __restrict__ b2,
    float* __restrict__ out)
{
    __shared__ __align__(16) unsigned short sA1[32 * 64 * 8];  // 32 KiB
    __shared__ __align__(16) unsigned short sA2[32 * 64 * 8];  // 32 KiB
    __shared__ __align__(16) float sb1[8 * 2 * 16];
    __shared__ __align__(16) float sb2[2 * 2 * 16];
    __shared__ __align__(16) float trbuf[WAVES][2048];         // 8 KiB per wave

    const int tid  = threadIdx.x;
    const int lane = tid & 63;
    const int wv   = tid >> 6;
    const int g    = lane >> 5;
    const int ln31 = lane & 31;

    // ---- stage W1 fragments: coalesced global reads, scattered LDS writes ----
    for (int idx = tid; idx < DIM * HID; idx += BLOCK) {
        int hid = idx & (HID - 1);
        int dim = idx >> 8;
        int c   = hid & 31, ht = hid >> 5;
        int j   = (dim & 3) | (((dim >> 3) & 1) << 2);
        int gg  = (dim >> 2) & 1;
        int kt  = dim >> 4;
        __bf16 bv = (__bf16)W1[idx];
        sA1[((ht * 4 + kt) * 64 + gg * 32 + c) * 8 + j] =
            __builtin_bit_cast(unsigned short, bv);
    }
    // ---- stage W2 fragments ----
    for (int idx = tid; idx < HID * DIM; idx += BLOCK) {
        int dim = idx & 63;
        int hid = idx >> 6;
        int c   = dim & 31, mt = dim >> 5;
        int hlo = hid & 15;
        int j   = (hlo & 3) | (((hlo >> 3) & 1) << 2);
        int gg  = (hlo >> 2) & 1;
        int kt2 = hid >> 4;
        __bf16 bv = (__bf16)W2[idx];
        sA2[((mt * 16 + kt2) * 64 + gg * 32 + c) * 8 + j] =
            __builtin_bit_cast(unsigned short, bv);
    }
    // ---- biases, permuted to C/D reg order ----
    if (tid < 256) {
        int r = tid & 15, gg = (tid >> 4) & 1, ht = tid >> 5;
        sb1[tid] = b1[ht * 32 + (r & 3) + 8 * (r >> 2) + 4 * gg];
    }
    if (tid < 64) {
        int r = tid & 15, gg = (tid >> 4) & 1, mt = tid >> 5;
        sb2[tid] = b2[mt * 32 + (r & 3) + 8 * (r >> 2) + 4 * gg];
    }

    // ---- out[0] = z0 (coalesced block-slice copy) ----
    {
        const f32x4* src = reinterpret_cast<const f32x4*>(z0 + (size_t)blockIdx.x * ROWS_PER_BLOCK * DIM);
        f32x4*       dst = reinterpret_cast<f32x4*>(out + (size_t)blockIdx.x * ROWS_PER_BLOCK * DIM);
        for (int i = tid; i < ROWS_PER_BLOCK * DIM / 4; i += BLOCK) dst[i] = src[i];
    }

    __syncthreads();

    const int rowbase = blockIdx.x * ROWS_PER_BLOCK + wv * ROWS_PER_WAVE;
    float* tb = trbuf[wv];

    const uint32x4* A1  = reinterpret_cast<const uint32x4*>(sA1);
    const uint32x4* A2  = reinterpret_cast<const uint32x4*>(sA2);
    const f32x4*    b1q = reinterpret_cast<const f32x4*>(sb1);
    const f32x4*    b2q = reinterpret_cast<const f32x4*>(sb2);

    // ---- z0 -> registers via per-wave LDS transpose (XOR-swizzled 16B) ----
    #pragma unroll
    for (int p = 0; p < 8; p++) {
        int batch  = (lane >> 4) + 4 * p;
        int linear = lane * 16 + p * 1024;
        f32x4 v = *reinterpret_cast<const f32x4*>(
            z0 + (size_t)(rowbase + batch) * DIM + (lane & 15) * 4);
        *reinterpret_cast<f32x4*>((char*)tb + (linear ^ ((batch & 7) << 4))) = v;
    }

    f32x16 za, zb;
    #pragma unroll
    for (int rp = 0; rp < 8; rp++) {
        int d    = (rp & 1) * 2 + 8 * (rp >> 1) + 4 * g;    // r = 2*rp, mt=0
        int byte = ln31 * 256 + d * 4;
        f32x2 v = *reinterpret_cast<f32x2*>((char*)tb + (byte ^ ((ln31 & 7) << 4)));
        za[2 * rp] = v[0]; za[2 * rp + 1] = v[1];
    }
    #pragma unroll
    for (int rp = 0; rp < 8; rp++) {
        int d    = 32 + (rp & 1) * 2 + 8 * (rp >> 1) + 4 * g;  // mt=1
        int byte = ln31 * 256 + d * 4;
        f32x2 v = *reinterpret_cast<f32x2*>((char*)tb + (byte ^ ((ln31 & 7) << 4)));
        zb[2 * rp] = v[0]; zb[2 * rp + 1] = v[1];
    }

    #pragma unroll 1
    for (int s = 0; s < TLEN - 1; s++) {
        const float h  = tarr[s + 1] - tarr[s];
        const float h2 = 0.5f * h;
        const float h3 = h * (1.0f / 3.0f);
        const float h6 = h * (1.0f / 6.0f);

        KOut k1 = feval(A1, A2, b1q, b2q, lane, g,
                        pack_lo(za), pack_hi(za), pack_lo(zb), pack_hi(zb));
        f32x16 zfa = axpy16(h6, k1.a, za), zfb = axpy16(h6, k1.b, zb);
        f32x16 pa  = axpy16(h2, k1.a, za), pb  = axpy16(h2, k1.b, zb);

        KOut k2 = feval(A1, A2, b1q, b2q, lane, g,
                        pack_lo(pa), pack_hi(pa), pack_lo(pb), pack_hi(pb));
        zfa = axpy16(h3, k2.a, zfa); zfb = axpy16(h3, k2.b, zfb);
        pa  = axpy16(h2, k2.a, za);  pb  = axpy16(h2, k2.b, zb);

        KOut k3 = feval(A1, A2, b1q, b2q, lane, g,
                        pack_lo(pa), pack_hi(pa), pack_lo(pb), pack_hi(pb));
        zfa = axpy16(h3, k3.a, zfa); zfb = axpy16(h3, k3.b, zfb);
        pa  = axpy16(h, k3.a, za);   pb  = axpy16(h, k3.b, zb);

        KOut k4 = feval(A1, A2, b1q, b2q, lane, g,
                        pack_lo(pa), pack_hi(pa), pack_lo(pb), pack_hi(pb));
        za = axpy16(h6, k4.a, zfa);  zb = axpy16(h6, k4.b, zfb);

        // ---- store trajectory[s+1] via per-wave LDS transpose ----
        #pragma unroll
        for (int rp = 0; rp < 8; rp++) {
            int d    = (rp & 1) * 2 + 8 * (rp >> 1) + 4 * g;
            int byte = ln31 * 256 + d * 4;
            f32x2 v; v[0] = za[2 * rp]; v[1] = za[2 * rp + 1];
            *reinterpret_cast<f32x2*>((char*)tb + (byte ^ ((ln31 & 7) << 4))) = v;
        }
        #pragma unroll
        for (int rp = 0; rp < 8; rp++) {
            int d    = 32 + (rp & 1) * 2 + 8 * (rp >> 1) + 4 * g;
            int byte = ln31 * 256 + d * 4;
            f32x2 v; v[0] = zb[2 * rp]; v[1] = zb[2 * rp + 1];
            *reinterpret_cast<f32x2*>((char*)tb + (byte ^ ((ln31 & 7) << 4))) = v;
        }
        float* obase = out + ((size_t)(s + 1) * BS + rowbase) * DIM;
        #pragma unroll
        for (int p = 0; p < 8; p++) {
            int batch  = (lane >> 4) + 4 * p;
            int linear = lane * 16 + p * 1024;
            f32x4 v = *reinterpret_cast<f32x4*>((char*)tb + (linear ^ ((batch & 7) << 4)));
            *reinterpret_cast<f32x4*>(obase + batch * DIM + (lane & 15) * 4) = v;
        }
    }
}

extern "C" void kernel_launch(void* const* d_in, const int* in_sizes, int n_in,
                              void* d_out, int out_size, void* d_ws, size_t ws_size,
                              hipStream_t stream) {
    const float* z0 = (const float*)d_in[0];
    const float* t  = (const float*)d_in[1];
    const float* W1 = (const float*)d_in[2];
    const float* b1 = (const float*)d_in[3];
    const float* W2 = (const float*)d_in[4];
    const float* b2 = (const float*)d_in[5];
    float* out = (float*)d_out;

    node_mfma_kernel<<<dim3(NBLOCKS), dim3(BLOCK), 0, stream>>>(
        z0, t, W1, b1, W2, b2, out);
}